// Round 14
// baseline (204.268 us; speedup 1.0000x reference)
//
#include <hip/hip_runtime.h>
#include <hip/hip_bf16.h>

typedef __bf16 bf16x8 __attribute__((ext_vector_type(8)));
typedef float f32x4 __attribute__((ext_vector_type(4)));

#define D_MODEL 1024
#define SEQ 2048
#define BATCH 4
#define HEADS 16
#define HD 64
#define M_TOT (BATCH * SEQ) /* 8192 */
#define QPW 4 /* 16-row q-blocks per wave */

// round-to-nearest-even fp32 -> bf16 bits
static __device__ __forceinline__ unsigned short f2bf(float f) {
  unsigned int u = __float_as_uint(f);
  unsigned int lsb = (u >> 16) & 1u;
  u += 0x7fffu + lsb;
  return (unsigned short)(u >> 16);
}

// async global->LDS, 16B per lane; LDS dest wave-uniform + lane*16 (verified R7)
static __device__ __forceinline__ void glds16(const void* g, void* l) {
  __builtin_amdgcn_global_load_lds(
      (const __attribute__((address_space(1))) unsigned int*)g,
      (__attribute__((address_space(3))) unsigned int*)l, 16, 0, 0);
}

// ---------------- fp32 -> bf16 conversion (vectorized) ----------------
__global__ __launch_bounds__(256) void cvt_x_kernel(const float* __restrict__ x,
                                                    unsigned short* __restrict__ xb,
                                                    int n4) {
  int i = blockIdx.x * 256 + threadIdx.x;
  if (i >= n4) return;
  const float4 v = reinterpret_cast<const float4*>(x)[i];
  ushort4 o;
  o.x = f2bf(v.x); o.y = f2bf(v.y); o.z = f2bf(v.z); o.w = f2bf(v.w);
  reinterpret_cast<ushort4*>(xb)[i] = o;
}

// ---------------- all four W [D][D] fp32 -> W^T [D][D] bf16, one launch -------
__global__ __launch_bounds__(256) void transW4_kernel(
    const float* __restrict__ Wq, const float* __restrict__ Wk,
    const float* __restrict__ Wv, const float* __restrict__ Wo,
    unsigned short* __restrict__ WqT, unsigned short* __restrict__ WkT,
    unsigned short* __restrict__ WvT, unsigned short* __restrict__ WoT) {
  const float* W;
  unsigned short* Wt;
  switch (blockIdx.z) {
    case 0: W = Wq; Wt = WqT; break;
    case 1: W = Wk; Wt = WkT; break;
    case 2: W = Wv; Wt = WvT; break;
    default: W = Wo; Wt = WoT; break;
  }
  __shared__ float t[32][33];
  int bx = blockIdx.x * 32;  // n base (output rows)
  int by = blockIdx.y * 32;  // k base
  int tx = threadIdx.x, ty = threadIdx.y;  // (32,8)
#pragma unroll
  for (int i = 0; i < 32; i += 8)
    t[ty + i][tx] = W[(size_t)(by + ty + i) * D_MODEL + bx + tx];
  __syncthreads();
#pragma unroll
  for (int i = 0; i < 32; i += 8)
    Wt[(size_t)(bx + ty + i) * D_MODEL + by + tx] = f2bf(t[tx][ty + i]);
}

// ---------------- QKV GEMM, 256^2 8-wave + T4 counted-vmcnt pipeline ----------
// R13 addressing (verified by absmax) + the one change R13 was missing per the
// regime gate: counted s_waitcnt vmcnt(8) instead of __syncthreads()'s
// vmcnt(0) drain. Loads for tile t+1 stay IN FLIGHT across the barrier:
//   prologue: STAGE(0); STAGE(1)                       [16 glds outstanding]
//   iter t:   vmcnt(8)  -> own tile-t loads done (newest 8 = t+1's, still fly)
//             s_barrier -> everyone's tile-t loads done (each counted its own)
//             compute(buf[t&1])
//             s_barrier -> all waves done reading buf[t&1] (no drain!)
//             STAGE(t+2) -> buf[t&1]  (overwrite-safe after that barrier)
// sched_barrier(0) pins ds_reads between the entry barrier and exit barrier
// (rule #18: hipcc can move memory ops past inline-asm waits otherwise).
__global__ __launch_bounds__(512) void gemm_qkv256_kernel(
    const unsigned short* __restrict__ A, const unsigned short* __restrict__ Bt,
    unsigned short* __restrict__ Qb, unsigned short* __restrict__ Kb,
    unsigned short* __restrict__ Vb, float qscale) {
  __shared__ __align__(16) unsigned short Als[2][256 * 64];
  __shared__ __align__(16) unsigned short Bls[2][256 * 64];

  const int tid = threadIdx.x;  // 0..511
  const int l = tid & 63;
  const int wave = tid >> 6;  // 0..7
  const int l15 = l & 15;
  const int lk = l >> 4;
  const int wm = wave >> 2;  // 0..1 (M half)
  const int wn = wave & 3;   // 0..3 (N quarter)

  // XCD-bijective swizzle: 384 = 8 x 48; 12 consecutive nid share an A panel.
  const int bid = blockIdx.x;
  const int nid = (bid & 7) * 48 + (bid >> 3);
  const int mblk = nid / 12, nblk = nid % 12;
  const int m0 = mblk << 8, n0 = nblk << 8;

  // staging: thread -> (row sr, 16B chunk), source col pre-swizzled so linear
  // LDS content is XOR-swizzled. (sr&7) is j-invariant (j*64 == 0 mod 8).
  const int sr = tid >> 3;                             // 0..63
  const int scb = ((tid & 7) * 16) ^ ((sr & 7) << 4);  // swizzled src col byte
  const char* Ab = (const char*)A;
  const char* Bb = (const char*)Bt;

  f32x4 acc[8][4] = {};

#define STAGE_T(t_, b_)                                                       \
  {                                                                           \
    const size_t kb_ = (size_t)(t_)*128;                                      \
    _Pragma("unroll") for (int j = 0; j < 4; ++j) {                           \
      glds16(Ab + (size_t)(m0 + j * 64 + sr) * 2048 + kb_ + scb,              \
             (char*)Als[b_] + j * 8192 + tid * 16);                           \
      glds16(Bb + (size_t)(n0 + j * 64 + sr) * 2048 + kb_ + scb,              \
             (char*)Bls[b_] + j * 8192 + tid * 16);                           \
    }                                                                         \
  }

  // prologue: tiles 0 and 1 in flight
  STAGE_T(0, 0);
  STAGE_T(1, 1);

#pragma unroll 1
  for (int t = 0; t < 16; ++t) {
    const int cur = t & 1;
    // wait own tile-t loads (newest 8 = tile t+1's stay in flight)
    if (t + 1 < 16) {
      asm volatile("s_waitcnt vmcnt(8)" ::: "memory");
    } else {
      asm volatile("s_waitcnt vmcnt(0)" ::: "memory");
    }
    __builtin_amdgcn_s_barrier();       // all waves' tile-t loads complete
    __builtin_amdgcn_sched_barrier(0);  // pin ds_reads below the barrier

    const char* albs = (const char*)Als[cur];
    const char* blbs = (const char*)Bls[cur];

    // B fragments once per K-tile (8 x ds_read_b128)
    bf16x8 bf[4][2];
#pragma unroll
    for (int ni = 0; ni < 4; ++ni)
#pragma unroll
      for (int kk = 0; kk < 2; ++kk) {
        const int br = wn * 64 + ni * 16 + l15;
        bf[ni][kk] = *reinterpret_cast<const bf16x8*>(
            blbs + br * 128 + ((kk * 64 + lk * 16) ^ ((br & 7) << 4)));
      }
    // 4 quadrant phases: {4 ds_read A + 16 MFMA}
#pragma unroll
    for (int q = 0; q < 4; ++q) {
      bf16x8 af[2][2];
#pragma unroll
      for (int d = 0; d < 2; ++d)
#pragma unroll
        for (int kk = 0; kk < 2; ++kk) {
          const int ar = wm * 128 + (q * 2 + d) * 16 + l15;
          af[d][kk] = *reinterpret_cast<const bf16x8*>(
              albs + ar * 128 + ((kk * 64 + lk * 16) ^ ((ar & 7) << 4)));
        }
#pragma unroll
      for (int kk = 0; kk < 2; ++kk)
#pragma unroll
        for (int d = 0; d < 2; ++d)
#pragma unroll
          for (int ni = 0; ni < 4; ++ni)
            acc[q * 2 + d][ni] = __builtin_amdgcn_mfma_f32_16x16x32_bf16(
                af[d][kk], bf[ni][kk], acc[q * 2 + d][ni], 0, 0, 0);
    }
    __builtin_amdgcn_sched_barrier(0);  // pin ds_reads above the exit barrier
    __builtin_amdgcn_s_barrier();       // buf[cur] free for overwrite (no drain)
    if (t + 2 < 16) STAGE_T(t + 2, cur);
  }
#undef STAGE_T

  // epilogue: which is block-uniform (n-tile 256 divides 1024)
  const int which = n0 >> 10;  // 0=Q 1=K 2=V
  const int ncol0 = n0 & 1023;
#pragma unroll
  for (int mi = 0; mi < 8; ++mi) {
#pragma unroll
    for (int ni = 0; ni < 4; ++ni) {
      const int grow0 = m0 + wm * 128 + mi * 16 + lk * 4;
      const int wcol = ncol0 + wn * 64 + ni * 16 + l15;
      if (which == 0) {
#pragma unroll
        for (int r = 0; r < 4; ++r)
          Qb[(size_t)(grow0 + r) * D_MODEL + wcol] = f2bf(acc[mi][ni][r] * qscale);
      } else if (which == 1) {
#pragma unroll
        for (int r = 0; r < 4; ++r)
          Kb[(size_t)(grow0 + r) * D_MODEL + wcol] = f2bf(acc[mi][ni][r]);
      } else {
        const int b = grow0 >> 11, s = grow0 & 2047;
        const int h = wcol >> 6, d = wcol & 63;
        ushort4 ov;
        ov.x = f2bf(acc[mi][ni][0]);
        ov.y = f2bf(acc[mi][ni][1]);
        ov.z = f2bf(acc[mi][ni][2]);
        ov.w = f2bf(acc[mi][ni][3]);
        *reinterpret_cast<ushort4*>(
            &Vb[((size_t)((b * HEADS + h) * HD + d)) * SEQ + s]) = ov;
      }
    }
  }
}

// ---------------- final GEMM: C[M,N] = A[M,K]*Bt^T + bias (fp32 out) ----------
__global__ __launch_bounds__(256) void gemm_out_kernel(
    const unsigned short* __restrict__ A, const unsigned short* __restrict__ Bt,
    float* __restrict__ out, const float* __restrict__ bias) {
  __shared__ __align__(16) unsigned short Als[128][72];
  __shared__ __align__(16) unsigned short Bls[128][72];

  const int tid = threadIdx.x;
  const int l = tid & 63;
  const int wave = tid >> 6;
  const int l15 = l & 15;
  const int lk = l >> 4;
  const int wm = wave >> 1, wn = wave & 1;

  const int nblocks_n = D_MODEL >> 7;
  const int mblk = blockIdx.x / nblocks_n;
  const int nblk = blockIdx.x % nblocks_n;
  const int m0 = mblk << 7, n0 = nblk << 7;

  f32x4 acc[4][4] = {};

  const int srow = tid >> 3;       // 0..31
  const int scol = (tid & 7) * 8;  // 0..56

  bf16x8 areg[4], breg[4];
#pragma unroll
  for (int i = 0; i < 4; ++i) {
    areg[i] = *reinterpret_cast<const bf16x8*>(&A[(size_t)(m0 + srow + i * 32) * D_MODEL + scol]);
    breg[i] = *reinterpret_cast<const bf16x8*>(&Bt[(size_t)(n0 + srow + i * 32) * D_MODEL + scol]);
  }

  for (int k0 = 0; k0 < D_MODEL; k0 += 64) {
    __syncthreads();
#pragma unroll
    for (int i = 0; i < 4; ++i) {
      *reinterpret_cast<bf16x8*>(&Als[srow + i * 32][scol]) = areg[i];
      *reinterpret_cast<bf16x8*>(&Bls[srow + i * 32][scol]) = breg[i];
    }
    __syncthreads();

    if (k0 + 64 < D_MODEL) {
#pragma unroll
      for (int i = 0; i < 4; ++i) {
        areg[i] = *reinterpret_cast<const bf16x8*>(
            &A[(size_t)(m0 + srow + i * 32) * D_MODEL + k0 + 64 + scol]);
        breg[i] = *reinterpret_cast<const bf16x8*>(
            &Bt[(size_t)(n0 + srow + i * 32) * D_MODEL + k0 + 64 + scol]);
      }
    }

#pragma unroll
    for (int kk = 0; kk < 2; ++kk) {
      bf16x8 af[4], bfr[4];
#pragma unroll
      for (int m = 0; m < 4; ++m)
        af[m] = *reinterpret_cast<const bf16x8*>(&Als[wm * 64 + m * 16 + l15][kk * 32 + lk * 8]);
#pragma unroll
      for (int n = 0; n < 4; ++n)
        bfr[n] = *reinterpret_cast<const bf16x8*>(&Bls[wn * 64 + n * 16 + l15][kk * 32 + lk * 8]);
#pragma unroll
      for (int m = 0; m < 4; ++m)
#pragma unroll
        for (int n = 0; n < 4; ++n)
          acc[m][n] = __builtin_amdgcn_mfma_f32_16x16x32_bf16(af[m], bfr[n], acc[m][n], 0, 0, 0);
    }
  }

#pragma unroll
  for (int m = 0; m < 4; ++m) {
#pragma unroll
    for (int n = 0; n < 4; ++n) {
      const int gm0 = m0 + wm * 64 + m * 16 + lk * 4;
      const int gn = n0 + wn * 64 + n * 16 + l15;
      const float bv = bias[gn];
#pragma unroll
      for (int r = 0; r < 4; ++r)
        out[(size_t)(gm0 + r) * D_MODEL + gn] = acc[m][n][r] + bv;
    }
  }
}

// ---------------- flash attention v9 (R12 frozen: 91.3 us, VGPR 128) ----------
__global__ __launch_bounds__(256) void attn_kernel(const unsigned short* __restrict__ Q,
                                                   const unsigned short* __restrict__ Kb,
                                                   const unsigned short* __restrict__ Vt,
                                                   unsigned short* __restrict__ o0,
                                                   unsigned short* __restrict__ o1,
                                                   float* __restrict__ l0,
                                                   float* __restrict__ l1) {
  __shared__ __align__(16) unsigned short Kls[64 * 64];
  __shared__ __align__(16) unsigned short Vls[64 * 64];

  const int tid = threadIdx.x;
  const int l = tid & 63;
  const int wave = tid >> 6;
  const int l15 = l & 15;
  const int lk = l >> 4;

  const int bid = blockIdx.x;
  const int nid = (bid & 7) * 128 + (bid >> 3);
  const int ks = nid & 1;
  const int qt = (nid >> 1) & 7;
  const int bh = nid >> 4;
  const int b = bh >> 4;
  const int h = bh & 15;

  const int qbase = b * SEQ + qt * 256 + wave * 64;
  const int kt0 = ks * 16;

  bf16x8 qf[QPW][2];
#pragma unroll
  for (int qb = 0; qb < QPW; ++qb)
#pragma unroll
    for (int kk = 0; kk < 2; ++kk)
      qf[qb][kk] = *reinterpret_cast<const bf16x8*>(
          &Q[(size_t)(qbase + qb * 16 + l15) * D_MODEL + h * HD + kk * 32 + lk * 8]);

  f32x4 acc[QPW][4] = {};
  float lsum[QPW] = {};

  const int srow = tid >> 2;  // 0..63
  const int sc = tid & 3;
  const int krow = (srow & 32) | ((srow & 4) << 2) | ((srow >> 1) & 12) | (srow & 3);

  const size_t kgbase = ((size_t)b * SEQ) * D_MODEL + h * HD;
  const size_t vgbase = ((size_t)(b * HEADS + h) * HD) * SEQ;

  char* klsb = (char*)Kls;
  char* vlsb = (char*)Vls;

  for (int kt = kt0; kt < kt0 + 16; ++kt) {
    __syncthreads();
    {
#pragma unroll
      for (int i = 0; i < 2; ++i) {
        uint4 kv = *reinterpret_cast<const uint4*>(
            &Kb[kgbase + (size_t)(kt * 64 + srow) * D_MODEL + sc * 8 + i * 32]);
        uint4 vv = *reinterpret_cast<const uint4*>(
            &Vt[vgbase + (size_t)srow * SEQ + kt * 64 + sc * 8 + i * 32]);
        *reinterpret_cast<uint4*>(
            klsb + krow * 128 + ((sc * 16 + i * 64) ^ ((krow & 7) << 4))) = kv;
        *reinterpret_cast<uint4*>(
            vlsb + srow * 128 + ((sc * 16 + i * 64) ^ ((srow & 7) << 4))) = vv;
      }
    }
    __syncthreads();

    f32x4 s[QPW][4] = {};
#pragma unroll
    for (int kk = 0; kk < 2; ++kk) {
      bf16x8 kf[4];
#pragma unroll
      for (int n = 0; n < 4; ++n)
        kf[n] = *reinterpret_cast<const bf16x8*>(
            klsb + (n * 16 + l15) * 128 + ((kk * 64 + lk * 16) ^ ((l15 & 7) << 4)));
#pragma unroll
      for (int qb = 0; qb < QPW; ++qb)
#pragma unroll
        for (int n = 0; n < 4; ++n)
          s[qb][n] = __builtin_amdgcn_mfma_f32_16x16x32_bf16(kf[n], qf[qb][kk], s[qb][n], 0, 0, 0);
    }

    bf16x8 pvv[QPW][2];
#pragma unroll
    for (int qb = 0; qb < QPW; ++qb) {
      float ps = 0.f;
#pragma unroll
      for (int n = 0; n < 4; ++n)
#pragma unroll
        for (int r = 0; r < 4; ++r) {
          float pp = __builtin_amdgcn_exp2f(s[qb][n][r]);
          ps += pp;
          pvv[qb][n >> 1][(n & 1) * 4 + r] = (__bf16)pp;
        }
      lsum[qb] += ps;
    }

#pragma unroll
    for (int kk = 0; kk < 2; ++kk) {
      bf16x8 vf[4];
#pragma unroll
      for (int nd = 0; nd < 4; ++nd)
        vf[nd] = *reinterpret_cast<const bf16x8*>(
            vlsb + (nd * 16 + l15) * 128 + ((kk * 64 + lk * 16) ^ ((l15 & 7) << 4)));
#pragma unroll
      for (int qb = 0; qb < QPW; ++qb)
#pragma unroll
        for (int nd = 0; nd < 4; ++nd)
          acc[qb][nd] = __builtin_amdgcn_mfma_f32_16x16x32_bf16(vf[nd], pvv[qb][kk], acc[qb][nd], 0, 0, 0);
    }
  }

  unsigned short* op = ks ? o1 : o0;
  float* lp = ks ? l1 : l0;
#pragma unroll
  for (int qb = 0; qb < QPW; ++qb) {
    float t = lsum[qb];
    t += __shfl_xor(t, 16);
    t += __shfl_xor(t, 32);
    const float inv = 1.0f / t;
    const int grow = qbase + qb * 16 + l15;
    const size_t row = (size_t)grow * D_MODEL + h * HD;
#pragma unroll
    for (int nd = 0; nd < 4; ++nd) {
      ushort4 ov;
      ov.x = f2bf(acc[qb][nd][0] * inv);
      ov.y = f2bf(acc[qb][nd][1] * inv);
      ov.z = f2bf(acc[qb][nd][2] * inv);
      ov.w = f2bf(acc[qb][nd][3] * inv);
      *reinterpret_cast<ushort4*>(&op[row + nd * 16 + lk * 4]) = ov;
    }
    if (l < 16) lp[grow * HEADS + h] = t;
  }
}

// ---------------- combine: O = (O0*l0 + O1*l1) / (l0+l1), in place over o0 ----
static __device__ __forceinline__ unsigned int comb2(unsigned int u0, unsigned int u1,
                                                     float w0, float w1) {
  float a0 = __uint_as_float((u0 & 0xffffu) << 16);
  float b0 = __uint_as_float(u0 & 0xffff0000u);
  float a1 = __uint_as_float((u1 & 0xffffu) << 16);
  float b1 = __uint_as_float(u1 & 0xffff0000u);
  unsigned int lo = f2bf(a0 * w0 + a1 * w1);
  unsigned int hi = f2bf(b0 * w0 + b1 * w1);
  return lo | (hi << 16);
}

__global__ __launch_bounds__(256) void combine_kernel(unsigned short* __restrict__ o0,
                                                      const unsigned short* __restrict__ o1,
                                                      const float* __restrict__ l0,
                                                      const float* __restrict__ l1) {
  const int i = blockIdx.x * 256 + threadIdx.x;
  const int row = i >> 7;
  const int h = (i & 127) >> 3;
  const float a = l0[row * HEADS + h];
  const float b = l1[row * HEADS + h];
  const float inv = 1.0f / (a + b);
  const float w0 = a * inv, w1 = b * inv;
  const uint4 x0 = reinterpret_cast<const uint4*>(o0)[i];
  const uint4 x1 = reinterpret_cast<const uint4*>(o1)[i];
  uint4 y;
  y.x = comb2(x0.x, x1.x, w0, w1);
  y.y = comb2(x0.y, x1.y, w0, w1);
  y.z = comb2(x0.z, x1.z, w0, w1);
  y.w = comb2(x0.w, x1.w, w0, w1);
  reinterpret_cast<uint4*>(o0)[i] = y;
}

extern "C" void kernel_launch(void* const* d_in, const int* in_sizes, int n_in,
                              void* d_out, int out_size, void* d_ws, size_t ws_size,
                              hipStream_t stream) {
  const float* x = (const float*)d_in[0];
  const float* Wq = (const float*)d_in[1];
  const float* Wk = (const float*)d_in[2];
  const float* Wv = (const float*)d_in[3];
  const float* Wo = (const float*)d_in[4];
  const float* bo = (const float*)d_in[5];

  char* ws = (char*)d_ws;
  const size_t MB = 1u << 20;
  unsigned short* xb = (unsigned short*)(ws + 0 * MB);    // 16 MB; reused as O-partial1
  unsigned short* WqT = (unsigned short*)(ws + 16 * MB);  // 2 MB (Bt base: Wq|Wk|Wv contiguous)
  unsigned short* WkT = (unsigned short*)(ws + 18 * MB);
  unsigned short* WvT = (unsigned short*)(ws + 20 * MB);
  unsigned short* WoT = (unsigned short*)(ws + 22 * MB);  // live until final GEMM
  unsigned short* Qb = (unsigned short*)(ws + 24 * MB);   // 16 MB
  unsigned short* Kb = (unsigned short*)(ws + 40 * MB);   // 16 MB
  unsigned short* Vt = (unsigned short*)(ws + 56 * MB);   // 16 MB
  unsigned short* ctx = (unsigned short*)(ws + 72 * MB);  // 16 MB; O-partial0 -> final
  float* l0 = (float*)(ws + 16 * MB);                     // over dead WqT (post-QKV)
  float* l1 = (float*)(ws + 16 * MB + 512 * 1024);

  int n4 = (M_TOT * D_MODEL) / 4;
  cvt_x_kernel<<<n4 / 256, 256, 0, stream>>>(x, xb, n4);

  transW4_kernel<<<dim3(32, 32, 4), dim3(32, 8), 0, stream>>>(Wq, Wk, Wv, Wo, WqT, WkT, WvT, WoT);

  // QKV 256^2 8-wave + counted vmcnt: 384 blocks x 512 thr.
  gemm_qkv256_kernel<<<384, 512, 0, stream>>>(xb, WqT, Qb, Kb, Vt, 0.125f * 1.44269504f);

  // key-split attention (partials over ctx & dead xb; l0/l1 over dead WqT)
  attn_kernel<<<BATCH * HEADS * (SEQ / 256) * 2, 256, 0, stream>>>(Qb, Kb, Vt, ctx, xb, l0, l1);
  combine_kernel<<<(M_TOT * D_MODEL / 8) / 256, 256, 0, stream>>>(ctx, xb, l0, l1);

  gemm_out_kernel<<<(M_TOT / 128) * (D_MODEL / 128), 256, 0, stream>>>(ctx, WoT, (float*)d_out, bo);
}

// Round 15
// 203.198 us; speedup vs baseline: 1.0053x; 1.0053x over previous
//
#include <hip/hip_runtime.h>
#include <hip/hip_bf16.h>

typedef __bf16 bf16x8 __attribute__((ext_vector_type(8)));
typedef float f32x4 __attribute__((ext_vector_type(4)));

#define D_MODEL 1024
#define SEQ 2048
#define BATCH 4
#define HEADS 16
#define HD 64
#define M_TOT (BATCH * SEQ) /* 8192 */
#define QPW 4 /* 16-row q-blocks per wave */

// round-to-nearest-even fp32 -> bf16 bits
static __device__ __forceinline__ unsigned short f2bf(float f) {
  unsigned int u = __float_as_uint(f);
  unsigned int lsb = (u >> 16) & 1u;
  u += 0x7fffu + lsb;
  return (unsigned short)(u >> 16);
}

// ---------------- fp32 -> bf16 conversion (vectorized) ----------------
__global__ __launch_bounds__(256) void cvt_x_kernel(const float* __restrict__ x,
                                                    unsigned short* __restrict__ xb,
                                                    int n4) {
  int i = blockIdx.x * 256 + threadIdx.x;
  if (i >= n4) return;
  const float4 v = reinterpret_cast<const float4*>(x)[i];
  ushort4 o;
  o.x = f2bf(v.x); o.y = f2bf(v.y); o.z = f2bf(v.z); o.w = f2bf(v.w);
  reinterpret_cast<ushort4*>(xb)[i] = o;
}

// ---------------- all four W [D][D] fp32 -> W^T [D][D] bf16, one launch -------
__global__ __launch_bounds__(256) void transW4_kernel(
    const float* __restrict__ Wq, const float* __restrict__ Wk,
    const float* __restrict__ Wv, const float* __restrict__ Wo,
    unsigned short* __restrict__ WqT, unsigned short* __restrict__ WkT,
    unsigned short* __restrict__ WvT, unsigned short* __restrict__ WoT) {
  const float* W;
  unsigned short* Wt;
  switch (blockIdx.z) {
    case 0: W = Wq; Wt = WqT; break;
    case 1: W = Wk; Wt = WkT; break;
    case 2: W = Wv; Wt = WvT; break;
    default: W = Wo; Wt = WoT; break;
  }
  __shared__ float t[32][33];
  int bx = blockIdx.x * 32;  // n base (output rows)
  int by = blockIdx.y * 32;  // k base
  int tx = threadIdx.x, ty = threadIdx.y;  // (32,8)
#pragma unroll
  for (int i = 0; i < 32; i += 8)
    t[ty + i][tx] = W[(size_t)(by + ty + i) * D_MODEL + bx + tx];
  __syncthreads();
#pragma unroll
  for (int i = 0; i < 32; i += 8)
    Wt[(size_t)(bx + ty + i) * D_MODEL + by + tx] = f2bf(t[tx][ty + i]);
}

// ---------------- merged QKV GEMM (R12 proven: ~61us, 4 blocks/CU) -----------
// R13/R14's 256^2 variants (2-phase and counted-vmcnt) were both neutral —
// regime gate confirmed: coarse phase-split without the full 8-phase fine
// interleave doesn't pay. Reverted to this proven structure.
__global__ __launch_bounds__(256) void gemm_qkv_kernel(
    const unsigned short* __restrict__ A, const unsigned short* __restrict__ WqT,
    const unsigned short* __restrict__ WkT, const unsigned short* __restrict__ WvT,
    unsigned short* __restrict__ Qb, unsigned short* __restrict__ Kb,
    unsigned short* __restrict__ Vb, float qscale) {
  __shared__ __align__(16) unsigned short Als[128][72];
  __shared__ __align__(16) unsigned short Bls[128][72];

  const int tid = threadIdx.x;
  const int l = tid & 63;
  const int wave = tid >> 6;
  const int l15 = l & 15;
  const int lk = l >> 4;
  const int wm = wave >> 1, wn = wave & 1;

  // XCD-bijective swizzle over 1536 = 8 x 192
  const int bid = blockIdx.x;
  const int nid = (bid & 7) * 192 + (bid >> 3);
  const int mblk = nid / 24;
  const int rem = nid % 24;
  const int which = rem >> 3;  // 0=Q 1=K 2=V
  const int nblk = rem & 7;
  const int m0 = mblk << 7, n0 = nblk << 7;

  const unsigned short* Bt = which == 0 ? WqT : (which == 1 ? WkT : WvT);
  const float scale = which == 0 ? qscale : 1.0f;

  f32x4 acc[4][4] = {};

  const int srow = tid >> 3;       // 0..31
  const int scol = (tid & 7) * 8;  // 0..56

  // preload tile 0 into registers
  bf16x8 areg[4], breg[4];
#pragma unroll
  for (int i = 0; i < 4; ++i) {
    areg[i] = *reinterpret_cast<const bf16x8*>(&A[(size_t)(m0 + srow + i * 32) * D_MODEL + scol]);
    breg[i] = *reinterpret_cast<const bf16x8*>(&Bt[(size_t)(n0 + srow + i * 32) * D_MODEL + scol]);
  }

  for (int k0 = 0; k0 < D_MODEL; k0 += 64) {
    __syncthreads();  // all waves done reading LDS from previous step
#pragma unroll
    for (int i = 0; i < 4; ++i) {
      *reinterpret_cast<bf16x8*>(&Als[srow + i * 32][scol]) = areg[i];
      *reinterpret_cast<bf16x8*>(&Bls[srow + i * 32][scol]) = breg[i];
    }
    __syncthreads();  // tile ready

    // issue next tile's loads; latency hides under the compute below
    if (k0 + 64 < D_MODEL) {
#pragma unroll
      for (int i = 0; i < 4; ++i) {
        areg[i] = *reinterpret_cast<const bf16x8*>(
            &A[(size_t)(m0 + srow + i * 32) * D_MODEL + k0 + 64 + scol]);
        breg[i] = *reinterpret_cast<const bf16x8*>(
            &Bt[(size_t)(n0 + srow + i * 32) * D_MODEL + k0 + 64 + scol]);
      }
    }

#pragma unroll
    for (int kk = 0; kk < 2; ++kk) {
      bf16x8 af[4], bfr[4];
#pragma unroll
      for (int m = 0; m < 4; ++m)
        af[m] = *reinterpret_cast<const bf16x8*>(&Als[wm * 64 + m * 16 + l15][kk * 32 + lk * 8]);
#pragma unroll
      for (int n = 0; n < 4; ++n)
        bfr[n] = *reinterpret_cast<const bf16x8*>(&Bls[wn * 64 + n * 16 + l15][kk * 32 + lk * 8]);
#pragma unroll
      for (int m = 0; m < 4; ++m)
#pragma unroll
        for (int n = 0; n < 4; ++n)
          acc[m][n] = __builtin_amdgcn_mfma_f32_16x16x32_bf16(af[m], bfr[n], acc[m][n], 0, 0, 0);
    }
  }

  unsigned short* out = which == 0 ? Qb : (which == 1 ? Kb : Vb);
#pragma unroll
  for (int m = 0; m < 4; ++m) {
#pragma unroll
    for (int n = 0; n < 4; ++n) {
      const int row0 = wm * 64 + m * 16 + lk * 4;
      const int col = wn * 64 + n * 16 + l15;
      const int gm0 = m0 + row0;
      const int gn = n0 + col;
      if (which < 2) {
#pragma unroll
        for (int r = 0; r < 4; ++r)
          out[(size_t)(gm0 + r) * D_MODEL + gn] = f2bf(acc[m][n][r] * scale);
      } else {
        int b = gm0 >> 11, s = gm0 & 2047;
        int h = gn >> 6, d = gn & 63;
        size_t base = ((size_t)((b * HEADS + h) * HD + d)) * SEQ + s;
#pragma unroll
        for (int r = 0; r < 4; ++r) out[base + r] = f2bf(acc[m][n][r]);
      }
    }
  }
}

// ---------------- final GEMM, BM=64 x BN=128 (occupancy fix, R11 lever) -------
// gemm_out was grid 512 = 2 blocks/CU (latency-bound, same pathology the QKV
// merge fixed). BM=64 halves per-block work -> grid 1024 = 4 blocks/CU; LDS
// 27.6KB, acc[2][4] -> ~90 VGPR. Staging/pipeline = R9 structure.
__global__ __launch_bounds__(256) void gemm_out_kernel(
    const unsigned short* __restrict__ A, const unsigned short* __restrict__ Bt,
    float* __restrict__ out, const float* __restrict__ bias) {
  __shared__ __align__(16) unsigned short Als[64][72];
  __shared__ __align__(16) unsigned short Bls[128][72];

  const int tid = threadIdx.x;
  const int l = tid & 63;
  const int wave = tid >> 6;
  const int l15 = l & 15;
  const int lk = l >> 4;
  const int wm = wave >> 1, wn = wave & 1;  // wave: 32-row half x 64-col half

  // XCD-bijective swizzle over 1024 = 8 x 128
  const int bid = blockIdx.x;
  const int nid = (bid & 7) * 128 + (bid >> 3);
  const int mblk = nid >> 3;       // 0..127
  const int nblk = nid & 7;        // 0..7
  const int m0 = mblk << 6, n0 = nblk << 7;

  f32x4 acc[2][4] = {};

  const int srow = tid >> 3;       // 0..31
  const int scol = (tid & 7) * 8;  // 0..56

  // preload tile 0: A rows {srow, +32} of 64; B rows {srow, +32, +64, +96}
  bf16x8 areg[2], breg[4];
#pragma unroll
  for (int i = 0; i < 2; ++i)
    areg[i] = *reinterpret_cast<const bf16x8*>(&A[(size_t)(m0 + srow + i * 32) * D_MODEL + scol]);
#pragma unroll
  for (int i = 0; i < 4; ++i)
    breg[i] = *reinterpret_cast<const bf16x8*>(&Bt[(size_t)(n0 + srow + i * 32) * D_MODEL + scol]);

  for (int k0 = 0; k0 < D_MODEL; k0 += 64) {
    __syncthreads();
#pragma unroll
    for (int i = 0; i < 2; ++i)
      *reinterpret_cast<bf16x8*>(&Als[srow + i * 32][scol]) = areg[i];
#pragma unroll
    for (int i = 0; i < 4; ++i)
      *reinterpret_cast<bf16x8*>(&Bls[srow + i * 32][scol]) = breg[i];
    __syncthreads();

    if (k0 + 64 < D_MODEL) {
#pragma unroll
      for (int i = 0; i < 2; ++i)
        areg[i] = *reinterpret_cast<const bf16x8*>(
            &A[(size_t)(m0 + srow + i * 32) * D_MODEL + k0 + 64 + scol]);
#pragma unroll
      for (int i = 0; i < 4; ++i)
        breg[i] = *reinterpret_cast<const bf16x8*>(
            &Bt[(size_t)(n0 + srow + i * 32) * D_MODEL + k0 + 64 + scol]);
    }

#pragma unroll
    for (int kk = 0; kk < 2; ++kk) {
      bf16x8 af[2], bfr[4];
#pragma unroll
      for (int m = 0; m < 2; ++m)
        af[m] = *reinterpret_cast<const bf16x8*>(&Als[wm * 32 + m * 16 + l15][kk * 32 + lk * 8]);
#pragma unroll
      for (int n = 0; n < 4; ++n)
        bfr[n] = *reinterpret_cast<const bf16x8*>(&Bls[wn * 64 + n * 16 + l15][kk * 32 + lk * 8]);
#pragma unroll
      for (int m = 0; m < 2; ++m)
#pragma unroll
        for (int n = 0; n < 4; ++n)
          acc[m][n] = __builtin_amdgcn_mfma_f32_16x16x32_bf16(af[m], bfr[n], acc[m][n], 0, 0, 0);
    }
  }

#pragma unroll
  for (int m = 0; m < 2; ++m) {
#pragma unroll
    for (int n = 0; n < 4; ++n) {
      const int gm0 = m0 + wm * 32 + m * 16 + lk * 4;
      const int gn = n0 + wn * 64 + n * 16 + l15;
      const float bv = bias[gn];
#pragma unroll
      for (int r = 0; r < 4; ++r)
        out[(size_t)(gm0 + r) * D_MODEL + gn] = acc[m][n][r] + bv;
    }
  }
}

// ---------------- flash attention v9 (R12 frozen: 91.3 us, VGPR 128) ----------
// Key-split x2, single-buffer LDS, serial stage hidden by 4 blocks/CU TLP.
// EXACT under no-max softmax: O = (O0*l0 + O1*l1)/(l0+l1).
__global__ __launch_bounds__(256) void attn_kernel(const unsigned short* __restrict__ Q,
                                                   const unsigned short* __restrict__ Kb,
                                                   const unsigned short* __restrict__ Vt,
                                                   unsigned short* __restrict__ o0,
                                                   unsigned short* __restrict__ o1,
                                                   float* __restrict__ l0,
                                                   float* __restrict__ l1) {
  __shared__ __align__(16) unsigned short Kls[64 * 64];
  __shared__ __align__(16) unsigned short Vls[64 * 64];

  const int tid = threadIdx.x;
  const int l = tid & 63;
  const int wave = tid >> 6;
  const int l15 = l & 15;
  const int lk = l >> 4;

  const int bid = blockIdx.x;
  const int nid = (bid & 7) * 128 + (bid >> 3);
  const int ks = nid & 1;
  const int qt = (nid >> 1) & 7;
  const int bh = nid >> 4;
  const int b = bh >> 4;
  const int h = bh & 15;

  const int qbase = b * SEQ + qt * 256 + wave * 64;
  const int kt0 = ks * 16;

  bf16x8 qf[QPW][2];
#pragma unroll
  for (int qb = 0; qb < QPW; ++qb)
#pragma unroll
    for (int kk = 0; kk < 2; ++kk)
      qf[qb][kk] = *reinterpret_cast<const bf16x8*>(
          &Q[(size_t)(qbase + qb * 16 + l15) * D_MODEL + h * HD + kk * 32 + lk * 8]);

  f32x4 acc[QPW][4] = {};
  float lsum[QPW] = {};

  const int srow = tid >> 2;  // 0..63
  const int sc = tid & 3;
  const int krow = (srow & 32) | ((srow & 4) << 2) | ((srow >> 1) & 12) | (srow & 3);

  const size_t kgbase = ((size_t)b * SEQ) * D_MODEL + h * HD;
  const size_t vgbase = ((size_t)(b * HEADS + h) * HD) * SEQ;

  char* klsb = (char*)Kls;
  char* vlsb = (char*)Vls;

  for (int kt = kt0; kt < kt0 + 16; ++kt) {
    __syncthreads();
    {
#pragma unroll
      for (int i = 0; i < 2; ++i) {
        uint4 kv = *reinterpret_cast<const uint4*>(
            &Kb[kgbase + (size_t)(kt * 64 + srow) * D_MODEL + sc * 8 + i * 32]);
        uint4 vv = *reinterpret_cast<const uint4*>(
            &Vt[vgbase + (size_t)srow * SEQ + kt * 64 + sc * 8 + i * 32]);
        *reinterpret_cast<uint4*>(
            klsb + krow * 128 + ((sc * 16 + i * 64) ^ ((krow & 7) << 4))) = kv;
        *reinterpret_cast<uint4*>(
            vlsb + srow * 128 + ((sc * 16 + i * 64) ^ ((srow & 7) << 4))) = vv;
      }
    }
    __syncthreads();

    f32x4 s[QPW][4] = {};
#pragma unroll
    for (int kk = 0; kk < 2; ++kk) {
      bf16x8 kf[4];
#pragma unroll
      for (int n = 0; n < 4; ++n)
        kf[n] = *reinterpret_cast<const bf16x8*>(
            klsb + (n * 16 + l15) * 128 + ((kk * 64 + lk * 16) ^ ((l15 & 7) << 4)));
#pragma unroll
      for (int qb = 0; qb < QPW; ++qb)
#pragma unroll
        for (int n = 0; n < 4; ++n)
          s[qb][n] = __builtin_amdgcn_mfma_f32_16x16x32_bf16(kf[n], qf[qb][kk], s[qb][n], 0, 0, 0);
    }

    bf16x8 pvv[QPW][2];
#pragma unroll
    for (int qb = 0; qb < QPW; ++qb) {
      float ps = 0.f;
#pragma unroll
      for (int n = 0; n < 4; ++n)
#pragma unroll
        for (int r = 0; r < 4; ++r) {
          float pp = __builtin_amdgcn_exp2f(s[qb][n][r]);
          ps += pp;
          pvv[qb][n >> 1][(n & 1) * 4 + r] = (__bf16)pp;
        }
      lsum[qb] += ps;
    }

#pragma unroll
    for (int kk = 0; kk < 2; ++kk) {
      bf16x8 vf[4];
#pragma unroll
      for (int nd = 0; nd < 4; ++nd)
        vf[nd] = *reinterpret_cast<const bf16x8*>(
            vlsb + (nd * 16 + l15) * 128 + ((kk * 64 + lk * 16) ^ ((l15 & 7) << 4)));
#pragma unroll
      for (int qb = 0; qb < QPW; ++qb)
#pragma unroll
        for (int nd = 0; nd < 4; ++nd)
          acc[qb][nd] = __builtin_amdgcn_mfma_f32_16x16x32_bf16(vf[nd], pvv[qb][kk], acc[qb][nd], 0, 0, 0);
    }
  }

  unsigned short* op = ks ? o1 : o0;
  float* lp = ks ? l1 : l0;
#pragma unroll
  for (int qb = 0; qb < QPW; ++qb) {
    float t = lsum[qb];
    t += __shfl_xor(t, 16);
    t += __shfl_xor(t, 32);
    const float inv = 1.0f / t;
    const int grow = qbase + qb * 16 + l15;
    const size_t row = (size_t)grow * D_MODEL + h * HD;
#pragma unroll
    for (int nd = 0; nd < 4; ++nd) {
      ushort4 ov;
      ov.x = f2bf(acc[qb][nd][0] * inv);
      ov.y = f2bf(acc[qb][nd][1] * inv);
      ov.z = f2bf(acc[qb][nd][2] * inv);
      ov.w = f2bf(acc[qb][nd][3] * inv);
      *reinterpret_cast<ushort4*>(&op[row + nd * 16 + lk * 4]) = ov;
    }
    if (l < 16) lp[grow * HEADS + h] = t;
  }
}

// ---------------- combine: O = (O0*l0 + O1*l1) / (l0+l1), in place over o0 ----
static __device__ __forceinline__ unsigned int comb2(unsigned int u0, unsigned int u1,
                                                     float w0, float w1) {
  float a0 = __uint_as_float((u0 & 0xffffu) << 16);
  float b0 = __uint_as_float(u0 & 0xffff0000u);
  float a1 = __uint_as_float((u1 & 0xffffu) << 16);
  float b1 = __uint_as_float(u1 & 0xffff0000u);
  unsigned int lo = f2bf(a0 * w0 + a1 * w1);
  unsigned int hi = f2bf(b0 * w0 + b1 * w1);
  return lo | (hi << 16);
}

__global__ __launch_bounds__(256) void combine_kernel(unsigned short* __restrict__ o0,
                                                      const unsigned short* __restrict__ o1,
                                                      const float* __restrict__ l0,
                                                      const float* __restrict__ l1) {
  const int i = blockIdx.x * 256 + threadIdx.x;
  const int row = i >> 7;
  const int h = (i & 127) >> 3;
  const float a = l0[row * HEADS + h];
  const float b = l1[row * HEADS + h];
  const float inv = 1.0f / (a + b);
  const float w0 = a * inv, w1 = b * inv;
  const uint4 x0 = reinterpret_cast<const uint4*>(o0)[i];
  const uint4 x1 = reinterpret_cast<const uint4*>(o1)[i];
  uint4 y;
  y.x = comb2(x0.x, x1.x, w0, w1);
  y.y = comb2(x0.y, x1.y, w0, w1);
  y.z = comb2(x0.z, x1.z, w0, w1);
  y.w = comb2(x0.w, x1.w, w0, w1);
  reinterpret_cast<uint4*>(o0)[i] = y;
}

extern "C" void kernel_launch(void* const* d_in, const int* in_sizes, int n_in,
                              void* d_out, int out_size, void* d_ws, size_t ws_size,
                              hipStream_t stream) {
  const float* x = (const float*)d_in[0];
  const float* Wq = (const float*)d_in[1];
  const float* Wk = (const float*)d_in[2];
  const float* Wv = (const float*)d_in[3];
  const float* Wo = (const float*)d_in[4];
  const float* bo = (const float*)d_in[5];

  char* ws = (char*)d_ws;
  const size_t MB = 1u << 20;
  unsigned short* xb = (unsigned short*)(ws + 0 * MB);    // 16 MB; reused as O-partial1
  unsigned short* WqT = (unsigned short*)(ws + 16 * MB);  // 2 MB
  unsigned short* WkT = (unsigned short*)(ws + 18 * MB);
  unsigned short* WvT = (unsigned short*)(ws + 20 * MB);
  unsigned short* WoT = (unsigned short*)(ws + 22 * MB);  // live until final GEMM
  unsigned short* Qb = (unsigned short*)(ws + 24 * MB);   // 16 MB
  unsigned short* Kb = (unsigned short*)(ws + 40 * MB);   // 16 MB
  unsigned short* Vt = (unsigned short*)(ws + 56 * MB);   // 16 MB
  unsigned short* ctx = (unsigned short*)(ws + 72 * MB);  // 16 MB; O-partial0 -> final
  float* l0 = (float*)(ws + 16 * MB);                     // over dead WqT (post-QKV)
  float* l1 = (float*)(ws + 16 * MB + 512 * 1024);

  int n4 = (M_TOT * D_MODEL) / 4;
  cvt_x_kernel<<<n4 / 256, 256, 0, stream>>>(x, xb, n4);

  transW4_kernel<<<dim3(32, 32, 4), dim3(32, 8), 0, stream>>>(Wq, Wk, Wv, Wo, WqT, WkT, WvT, WoT);

  // merged QKV (R12 proven): grid 1536 -> 4 blocks/CU.
  gemm_qkv_kernel<<<3 * (M_TOT / 128) * (D_MODEL / 128), 256, 0, stream>>>(
      xb, WqT, WkT, WvT, Qb, Kb, Vt, 0.125f * 1.44269504f);

  // key-split attention (partials over ctx & dead xb; l0/l1 over dead WqT)
  attn_kernel<<<BATCH * HEADS * (SEQ / 256) * 2, 256, 0, stream>>>(Qb, Kb, Vt, ctx, xb, l0, l1);
  combine_kernel<<<(M_TOT * D_MODEL / 8) / 256, 256, 0, stream>>>(ctx, xb, l0, l1);

  // final GEMM: BM=64 tiles -> grid 1024 = 4 blocks/CU.
  gemm_out_kernel<<<(M_TOT / 64) * (D_MODEL / 128), 256, 0, stream>>>(ctx, WoT, (float*)d_out, bo);
}

// Round 16
// 200.308 us; speedup vs baseline: 1.0198x; 1.0144x over previous
//
#include <hip/hip_runtime.h>
#include <hip/hip_bf16.h>

typedef __bf16 bf16x8 __attribute__((ext_vector_type(8)));
typedef float f32x4 __attribute__((ext_vector_type(4)));

#define D_MODEL 1024
#define SEQ 2048
#define BATCH 4
#define HEADS 16
#define HD 64
#define M_TOT (BATCH * SEQ) /* 8192 */
#define QPW 4 /* 16-row q-blocks per wave */

// round-to-nearest-even fp32 -> bf16 bits
static __device__ __forceinline__ unsigned short f2bf(float f) {
  unsigned int u = __float_as_uint(f);
  unsigned int lsb = (u >> 16) & 1u;
  u += 0x7fffu + lsb;
  return (unsigned short)(u >> 16);
}

// ---------------- fp32 -> bf16 conversion (vectorized) ----------------
__global__ __launch_bounds__(256) void cvt_x_kernel(const float* __restrict__ x,
                                                    unsigned short* __restrict__ xb,
                                                    int n4) {
  int i = blockIdx.x * 256 + threadIdx.x;
  if (i >= n4) return;
  const float4 v = reinterpret_cast<const float4*>(x)[i];
  ushort4 o;
  o.x = f2bf(v.x); o.y = f2bf(v.y); o.z = f2bf(v.z); o.w = f2bf(v.w);
  reinterpret_cast<ushort4*>(xb)[i] = o;
}

// ---------------- all four W [D][D] fp32 -> W^T [D][D] bf16, one launch -------
__global__ __launch_bounds__(256) void transW4_kernel(
    const float* __restrict__ Wq, const float* __restrict__ Wk,
    const float* __restrict__ Wv, const float* __restrict__ Wo,
    unsigned short* __restrict__ WqT, unsigned short* __restrict__ WkT,
    unsigned short* __restrict__ WvT, unsigned short* __restrict__ WoT) {
  const float* W;
  unsigned short* Wt;
  switch (blockIdx.z) {
    case 0: W = Wq; Wt = WqT; break;
    case 1: W = Wk; Wt = WkT; break;
    case 2: W = Wv; Wt = WvT; break;
    default: W = Wo; Wt = WoT; break;
  }
  __shared__ float t[32][33];
  int bx = blockIdx.x * 32;  // n base (output rows)
  int by = blockIdx.y * 32;  // k base
  int tx = threadIdx.x, ty = threadIdx.y;  // (32,8)
#pragma unroll
  for (int i = 0; i < 32; i += 8)
    t[ty + i][tx] = W[(size_t)(by + ty + i) * D_MODEL + bx + tx];
  __syncthreads();
#pragma unroll
  for (int i = 0; i < 32; i += 8)
    Wt[(size_t)(bx + ty + i) * D_MODEL + by + tx] = f2bf(t[tx][ty + i]);
}

// ---------------- merged QKV GEMM (R12 proven: ~61us, 4 blocks/CU) -----------
// R13/R14's 256^2 variants (2-phase and counted-vmcnt) were both neutral —
// regime gate confirmed: at K=1024 (16 k-steps) the deep-pipeline machinery
// doesn't pay; 128^2 @ 4 blocks/CU reg-prefetch is this shape's plateau.
__global__ __launch_bounds__(256) void gemm_qkv_kernel(
    const unsigned short* __restrict__ A, const unsigned short* __restrict__ WqT,
    const unsigned short* __restrict__ WkT, const unsigned short* __restrict__ WvT,
    unsigned short* __restrict__ Qb, unsigned short* __restrict__ Kb,
    unsigned short* __restrict__ Vb, float qscale) {
  __shared__ __align__(16) unsigned short Als[128][72];
  __shared__ __align__(16) unsigned short Bls[128][72];

  const int tid = threadIdx.x;
  const int l = tid & 63;
  const int wave = tid >> 6;
  const int l15 = l & 15;
  const int lk = l >> 4;
  const int wm = wave >> 1, wn = wave & 1;

  // XCD-bijective swizzle over 1536 = 8 x 192
  const int bid = blockIdx.x;
  const int nid = (bid & 7) * 192 + (bid >> 3);
  const int mblk = nid / 24;
  const int rem = nid % 24;
  const int which = rem >> 3;  // 0=Q 1=K 2=V
  const int nblk = rem & 7;
  const int m0 = mblk << 7, n0 = nblk << 7;

  const unsigned short* Bt = which == 0 ? WqT : (which == 1 ? WkT : WvT);
  const float scale = which == 0 ? qscale : 1.0f;

  f32x4 acc[4][4] = {};

  const int srow = tid >> 3;       // 0..31
  const int scol = (tid & 7) * 8;  // 0..56

  // preload tile 0 into registers
  bf16x8 areg[4], breg[4];
#pragma unroll
  for (int i = 0; i < 4; ++i) {
    areg[i] = *reinterpret_cast<const bf16x8*>(&A[(size_t)(m0 + srow + i * 32) * D_MODEL + scol]);
    breg[i] = *reinterpret_cast<const bf16x8*>(&Bt[(size_t)(n0 + srow + i * 32) * D_MODEL + scol]);
  }

  for (int k0 = 0; k0 < D_MODEL; k0 += 64) {
    __syncthreads();  // all waves done reading LDS from previous step
#pragma unroll
    for (int i = 0; i < 4; ++i) {
      *reinterpret_cast<bf16x8*>(&Als[srow + i * 32][scol]) = areg[i];
      *reinterpret_cast<bf16x8*>(&Bls[srow + i * 32][scol]) = breg[i];
    }
    __syncthreads();  // tile ready

    // issue next tile's loads; latency hides under the compute below
    if (k0 + 64 < D_MODEL) {
#pragma unroll
      for (int i = 0; i < 4; ++i) {
        areg[i] = *reinterpret_cast<const bf16x8*>(
            &A[(size_t)(m0 + srow + i * 32) * D_MODEL + k0 + 64 + scol]);
        breg[i] = *reinterpret_cast<const bf16x8*>(
            &Bt[(size_t)(n0 + srow + i * 32) * D_MODEL + k0 + 64 + scol]);
      }
    }

#pragma unroll
    for (int kk = 0; kk < 2; ++kk) {
      bf16x8 af[4], bfr[4];
#pragma unroll
      for (int m = 0; m < 4; ++m)
        af[m] = *reinterpret_cast<const bf16x8*>(&Als[wm * 64 + m * 16 + l15][kk * 32 + lk * 8]);
#pragma unroll
      for (int n = 0; n < 4; ++n)
        bfr[n] = *reinterpret_cast<const bf16x8*>(&Bls[wn * 64 + n * 16 + l15][kk * 32 + lk * 8]);
#pragma unroll
      for (int m = 0; m < 4; ++m)
#pragma unroll
        for (int n = 0; n < 4; ++n)
          acc[m][n] = __builtin_amdgcn_mfma_f32_16x16x32_bf16(af[m], bfr[n], acc[m][n], 0, 0, 0);
    }
  }

  unsigned short* out = which == 0 ? Qb : (which == 1 ? Kb : Vb);
#pragma unroll
  for (int m = 0; m < 4; ++m) {
#pragma unroll
    for (int n = 0; n < 4; ++n) {
      const int row0 = wm * 64 + m * 16 + lk * 4;
      const int col = wn * 64 + n * 16 + l15;
      const int gm0 = m0 + row0;
      const int gn = n0 + col;
      if (which < 2) {
#pragma unroll
        for (int r = 0; r < 4; ++r)
          out[(size_t)(gm0 + r) * D_MODEL + gn] = f2bf(acc[m][n][r] * scale);
      } else {
        int b = gm0 >> 11, s = gm0 & 2047;
        int h = gn >> 6, d = gn & 63;
        size_t base = ((size_t)((b * HEADS + h) * HD + d)) * SEQ + s;
#pragma unroll
        for (int r = 0; r < 4; ++r) out[base + r] = f2bf(acc[m][n][r]);
      }
    }
  }
}

// ---------------- final GEMM (exact R12 version: 128^2, grid 512) -------------
// R15's BM=64 reshape was neutral-to-negative: gemm_out is write-floor +
// B-reuse bound, not latency-bound. Reverted to the best-measured variant.
__global__ __launch_bounds__(256) void gemm_out_kernel(
    const unsigned short* __restrict__ A, const unsigned short* __restrict__ Bt,
    float* __restrict__ out, const float* __restrict__ bias) {
  __shared__ __align__(16) unsigned short Als[128][72];
  __shared__ __align__(16) unsigned short Bls[128][72];

  const int tid = threadIdx.x;
  const int l = tid & 63;
  const int wave = tid >> 6;
  const int l15 = l & 15;
  const int lk = l >> 4;
  const int wm = wave >> 1, wn = wave & 1;

  const int nblocks_n = D_MODEL >> 7;
  const int mblk = blockIdx.x / nblocks_n;
  const int nblk = blockIdx.x % nblocks_n;
  const int m0 = mblk << 7, n0 = nblk << 7;

  f32x4 acc[4][4] = {};

  const int srow = tid >> 3;       // 0..31
  const int scol = (tid & 7) * 8;  // 0..56

  bf16x8 areg[4], breg[4];
#pragma unroll
  for (int i = 0; i < 4; ++i) {
    areg[i] = *reinterpret_cast<const bf16x8*>(&A[(size_t)(m0 + srow + i * 32) * D_MODEL + scol]);
    breg[i] = *reinterpret_cast<const bf16x8*>(&Bt[(size_t)(n0 + srow + i * 32) * D_MODEL + scol]);
  }

  for (int k0 = 0; k0 < D_MODEL; k0 += 64) {
    __syncthreads();
#pragma unroll
    for (int i = 0; i < 4; ++i) {
      *reinterpret_cast<bf16x8*>(&Als[srow + i * 32][scol]) = areg[i];
      *reinterpret_cast<bf16x8*>(&Bls[srow + i * 32][scol]) = breg[i];
    }
    __syncthreads();

    if (k0 + 64 < D_MODEL) {
#pragma unroll
      for (int i = 0; i < 4; ++i) {
        areg[i] = *reinterpret_cast<const bf16x8*>(
            &A[(size_t)(m0 + srow + i * 32) * D_MODEL + k0 + 64 + scol]);
        breg[i] = *reinterpret_cast<const bf16x8*>(
            &Bt[(size_t)(n0 + srow + i * 32) * D_MODEL + k0 + 64 + scol]);
      }
    }

#pragma unroll
    for (int kk = 0; kk < 2; ++kk) {
      bf16x8 af[4], bfr[4];
#pragma unroll
      for (int m = 0; m < 4; ++m)
        af[m] = *reinterpret_cast<const bf16x8*>(&Als[wm * 64 + m * 16 + l15][kk * 32 + lk * 8]);
#pragma unroll
      for (int n = 0; n < 4; ++n)
        bfr[n] = *reinterpret_cast<const bf16x8*>(&Bls[wn * 64 + n * 16 + l15][kk * 32 + lk * 8]);
#pragma unroll
      for (int m = 0; m < 4; ++m)
#pragma unroll
        for (int n = 0; n < 4; ++n)
          acc[m][n] = __builtin_amdgcn_mfma_f32_16x16x32_bf16(af[m], bfr[n], acc[m][n], 0, 0, 0);
    }
  }

#pragma unroll
  for (int m = 0; m < 4; ++m) {
#pragma unroll
    for (int n = 0; n < 4; ++n) {
      const int gm0 = m0 + wm * 64 + m * 16 + lk * 4;
      const int gn = n0 + wn * 64 + n * 16 + l15;
      const float bv = bias[gn];
#pragma unroll
      for (int r = 0; r < 4; ++r)
        out[(size_t)(gm0 + r) * D_MODEL + gn] = acc[m][n][r] + bv;
    }
  }
}

// ---------------- flash attention v9 (R12 frozen: 91.3 us, VGPR 128) ----------
// Key-split x2, single-buffer LDS, serial stage hidden by 4 blocks/CU TLP.
// EXACT under no-max softmax: O = (O0*l0 + O1*l1)/(l0+l1).
__global__ __launch_bounds__(256) void attn_kernel(const unsigned short* __restrict__ Q,
                                                   const unsigned short* __restrict__ Kb,
                                                   const unsigned short* __restrict__ Vt,
                                                   unsigned short* __restrict__ o0,
                                                   unsigned short* __restrict__ o1,
                                                   float* __restrict__ l0,
                                                   float* __restrict__ l1) {
  __shared__ __align__(16) unsigned short Kls[64 * 64];
  __shared__ __align__(16) unsigned short Vls[64 * 64];

  const int tid = threadIdx.x;
  const int l = tid & 63;
  const int wave = tid >> 6;
  const int l15 = l & 15;
  const int lk = l >> 4;

  const int bid = blockIdx.x;
  const int nid = (bid & 7) * 128 + (bid >> 3);
  const int ks = nid & 1;
  const int qt = (nid >> 1) & 7;
  const int bh = nid >> 4;
  const int b = bh >> 4;
  const int h = bh & 15;

  const int qbase = b * SEQ + qt * 256 + wave * 64;
  const int kt0 = ks * 16;

  bf16x8 qf[QPW][2];
#pragma unroll
  for (int qb = 0; qb < QPW; ++qb)
#pragma unroll
    for (int kk = 0; kk < 2; ++kk)
      qf[qb][kk] = *reinterpret_cast<const bf16x8*>(
          &Q[(size_t)(qbase + qb * 16 + l15) * D_MODEL + h * HD + kk * 32 + lk * 8]);

  f32x4 acc[QPW][4] = {};
  float lsum[QPW] = {};

  const int srow = tid >> 2;  // 0..63
  const int sc = tid & 3;
  const int krow = (srow & 32) | ((srow & 4) << 2) | ((srow >> 1) & 12) | (srow & 3);

  const size_t kgbase = ((size_t)b * SEQ) * D_MODEL + h * HD;
  const size_t vgbase = ((size_t)(b * HEADS + h) * HD) * SEQ;

  char* klsb = (char*)Kls;
  char* vlsb = (char*)Vls;

  for (int kt = kt0; kt < kt0 + 16; ++kt) {
    __syncthreads();
    {
#pragma unroll
      for (int i = 0; i < 2; ++i) {
        uint4 kv = *reinterpret_cast<const uint4*>(
            &Kb[kgbase + (size_t)(kt * 64 + srow) * D_MODEL + sc * 8 + i * 32]);
        uint4 vv = *reinterpret_cast<const uint4*>(
            &Vt[vgbase + (size_t)srow * SEQ + kt * 64 + sc * 8 + i * 32]);
        *reinterpret_cast<uint4*>(
            klsb + krow * 128 + ((sc * 16 + i * 64) ^ ((krow & 7) << 4))) = kv;
        *reinterpret_cast<uint4*>(
            vlsb + srow * 128 + ((sc * 16 + i * 64) ^ ((srow & 7) << 4))) = vv;
      }
    }
    __syncthreads();

    f32x4 s[QPW][4] = {};
#pragma unroll
    for (int kk = 0; kk < 2; ++kk) {
      bf16x8 kf[4];
#pragma unroll
      for (int n = 0; n < 4; ++n)
        kf[n] = *reinterpret_cast<const bf16x8*>(
            klsb + (n * 16 + l15) * 128 + ((kk * 64 + lk * 16) ^ ((l15 & 7) << 4)));
#pragma unroll
      for (int qb = 0; qb < QPW; ++qb)
#pragma unroll
        for (int n = 0; n < 4; ++n)
          s[qb][n] = __builtin_amdgcn_mfma_f32_16x16x32_bf16(kf[n], qf[qb][kk], s[qb][n], 0, 0, 0);
    }

    bf16x8 pvv[QPW][2];
#pragma unroll
    for (int qb = 0; qb < QPW; ++qb) {
      float ps = 0.f;
#pragma unroll
      for (int n = 0; n < 4; ++n)
#pragma unroll
        for (int r = 0; r < 4; ++r) {
          float pp = __builtin_amdgcn_exp2f(s[qb][n][r]);
          ps += pp;
          pvv[qb][n >> 1][(n & 1) * 4 + r] = (__bf16)pp;
        }
      lsum[qb] += ps;
    }

#pragma unroll
    for (int kk = 0; kk < 2; ++kk) {
      bf16x8 vf[4];
#pragma unroll
      for (int nd = 0; nd < 4; ++nd)
        vf[nd] = *reinterpret_cast<const bf16x8*>(
            vlsb + (nd * 16 + l15) * 128 + ((kk * 64 + lk * 16) ^ ((l15 & 7) << 4)));
#pragma unroll
      for (int qb = 0; qb < QPW; ++qb)
#pragma unroll
        for (int nd = 0; nd < 4; ++nd)
          acc[qb][nd] = __builtin_amdgcn_mfma_f32_16x16x32_bf16(vf[nd], pvv[qb][kk], acc[qb][nd], 0, 0, 0);
    }
  }

  unsigned short* op = ks ? o1 : o0;
  float* lp = ks ? l1 : l0;
#pragma unroll
  for (int qb = 0; qb < QPW; ++qb) {
    float t = lsum[qb];
    t += __shfl_xor(t, 16);
    t += __shfl_xor(t, 32);
    const float inv = 1.0f / t;
    const int grow = qbase + qb * 16 + l15;
    const size_t row = (size_t)grow * D_MODEL + h * HD;
#pragma unroll
    for (int nd = 0; nd < 4; ++nd) {
      ushort4 ov;
      ov.x = f2bf(acc[qb][nd][0] * inv);
      ov.y = f2bf(acc[qb][nd][1] * inv);
      ov.z = f2bf(acc[qb][nd][2] * inv);
      ov.w = f2bf(acc[qb][nd][3] * inv);
      *reinterpret_cast<ushort4*>(&op[row + nd * 16 + lk * 4]) = ov;
    }
    if (l < 16) lp[grow * HEADS + h] = t;
  }
}

// ---------------- combine: O = (O0*l0 + O1*l1) / (l0+l1), in place over o0 ----
static __device__ __forceinline__ unsigned int comb2(unsigned int u0, unsigned int u1,
                                                     float w0, float w1) {
  float a0 = __uint_as_float((u0 & 0xffffu) << 16);
  float b0 = __uint_as_float(u0 & 0xffff0000u);
  float a1 = __uint_as_float((u1 & 0xffffu) << 16);
  float b1 = __uint_as_float(u1 & 0xffff0000u);
  unsigned int lo = f2bf(a0 * w0 + a1 * w1);
  unsigned int hi = f2bf(b0 * w0 + b1 * w1);
  return lo | (hi << 16);
}

__global__ __launch_bounds__(256) void combine_kernel(unsigned short* __restrict__ o0,
                                                      const unsigned short* __restrict__ o1,
                                                      const float* __restrict__ l0,
                                                      const float* __restrict__ l1) {
  const int i = blockIdx.x * 256 + threadIdx.x;
  const int row = i >> 7;
  const int h = (i & 127) >> 3;
  const float a = l0[row * HEADS + h];
  const float b = l1[row * HEADS + h];
  const float inv = 1.0f / (a + b);
  const float w0 = a * inv, w1 = b * inv;
  const uint4 x0 = reinterpret_cast<const uint4*>(o0)[i];
  const uint4 x1 = reinterpret_cast<const uint4*>(o1)[i];
  uint4 y;
  y.x = comb2(x0.x, x1.x, w0, w1);
  y.y = comb2(x0.y, x1.y, w0, w1);
  y.z = comb2(x0.z, x1.z, w0, w1);
  y.w = comb2(x0.w, x1.w, w0, w1);
  reinterpret_cast<uint4*>(o0)[i] = y;
}

extern "C" void kernel_launch(void* const* d_in, const int* in_sizes, int n_in,
                              void* d_out, int out_size, void* d_ws, size_t ws_size,
                              hipStream_t stream) {
  const float* x = (const float*)d_in[0];
  const float* Wq = (const float*)d_in[1];
  const float* Wk = (const float*)d_in[2];
  const float* Wv = (const float*)d_in[3];
  const float* Wo = (const float*)d_in[4];
  const float* bo = (const float*)d_in[5];

  char* ws = (char*)d_ws;
  const size_t MB = 1u << 20;
  unsigned short* xb = (unsigned short*)(ws + 0 * MB);    // 16 MB; reused as O-partial1
  unsigned short* WqT = (unsigned short*)(ws + 16 * MB);  // 2 MB
  unsigned short* WkT = (unsigned short*)(ws + 18 * MB);
  unsigned short* WvT = (unsigned short*)(ws + 20 * MB);
  unsigned short* WoT = (unsigned short*)(ws + 22 * MB);  // live until final GEMM
  unsigned short* Qb = (unsigned short*)(ws + 24 * MB);   // 16 MB
  unsigned short* Kb = (unsigned short*)(ws + 40 * MB);   // 16 MB
  unsigned short* Vt = (unsigned short*)(ws + 56 * MB);   // 16 MB
  unsigned short* ctx = (unsigned short*)(ws + 72 * MB);  // 16 MB; O-partial0 -> final
  float* l0 = (float*)(ws + 16 * MB);                     // over dead WqT (post-QKV)
  float* l1 = (float*)(ws + 16 * MB + 512 * 1024);

  int n4 = (M_TOT * D_MODEL) / 4;
  cvt_x_kernel<<<n4 / 256, 256, 0, stream>>>(x, xb, n4);

  transW4_kernel<<<dim3(32, 32, 4), dim3(32, 8), 0, stream>>>(Wq, Wk, Wv, Wo, WqT, WkT, WvT, WoT);

  // merged QKV (R12 proven): grid 1536 -> 4 blocks/CU.
  gemm_qkv_kernel<<<3 * (M_TOT / 128) * (D_MODEL / 128), 256, 0, stream>>>(
      xb, WqT, WkT, WvT, Qb, Kb, Vt, 0.125f * 1.44269504f);

  // key-split attention (partials over ctx & dead xb; l0/l1 over dead WqT)
  attn_kernel<<<BATCH * HEADS * (SEQ / 256) * 2, 256, 0, stream>>>(Qb, Kb, Vt, ctx, xb, l0, l1);
  combine_kernel<<<(M_TOT * D_MODEL / 8) / 256, 256, 0, stream>>>(ctx, xb, l0, l1);

  // final GEMM (R12 proven): 128^2, grid 512.
  gemm_out_kernel<<<(M_TOT / 128) * (D_MODEL / 128), 256, 0, stream>>>(ctx, WoT, (float*)d_out, bo);
}